// Round 1
// baseline (1178.409 us; speedup 1.0000x reference)
//
#include <hip/hip_runtime.h>
#include <math.h>

// Problem: B=8, C=256, H=25, W=512
// ws layout (float offsets):
//   X     @ 0          (26,214,400)  scnn1 output, stored in LOGICAL (reversed) order
//   Y     @ 26214400   (26,214,400)  scnn2 output, logical order
//   Mt    @ 52428800   (65,536)      M transposed: Mt[i*256+o] = w_msg[o,i,4,0]
//   coef1 @ 52494336   (512)         bn1 affine: a[c], b[c]
//   coef2 @ 52494848   (512)         bn2 affine
//   wh    @ 52495360   (19,200)      folded conv/h-reduce weights [c][hh][kw]
//   r     @ 52514560   (8,192)       reduced map (8 x 1024)
// total = 52,522,752 floats = 210,091,008 bytes of d_ws required.

#define X_OFF      0
#define Y_OFF      26214400
#define MT_OFF     52428800
#define COEF1_OFF  52494336
#define COEF2_OFF  52494848
#define WH_OFF     52495360
#define R_OFF      52514560

__global__ __launch_bounds__(256) void prep_mt(const float* __restrict__ wmsg,
                                               float* __restrict__ Mt)
{
    int idx = blockIdx.x * 256 + threadIdx.x;   // 65536 total
    int i = idx >> 8, o = idx & 255;
    Mt[idx] = wmsg[(o * 256 + i) * 9 + 4];      // Mt[i][o] = M[o][i]
}

// wh[c][hh][kw] = sum_kh (valid) w2[hh-kh+1] * (sum_o w1[o]*w_up2[o,c,kh,kw])
__global__ __launch_bounds__(256) void prep_wh(const float* __restrict__ wup2,
                                               const float* __restrict__ w1,
                                               const float* __restrict__ w2,
                                               float* __restrict__ wh)
{
    int idx = blockIdx.x * 256 + threadIdx.x;
    if (idx >= 768) return;
    int c = idx / 3, kw = idx % 3;
    float wr[3] = {0.f, 0.f, 0.f};
    for (int o = 0; o < 256; ++o) {
        float w1o = w1[o];
        const float* base = wup2 + ((size_t)(o * 256 + c) * 3) * 3 + kw;
        wr[0] = fmaf(w1o, base[0], wr[0]);
        wr[1] = fmaf(w1o, base[3], wr[1]);
        wr[2] = fmaf(w1o, base[6], wr[2]);
    }
    for (int hh = 0; hh < 25; ++hh) {
        float s = 0.f;
        #pragma unroll
        for (int kh = 0; kh < 3; ++kh) {
            int m = hh - kh + 1;
            if (m >= 0 && m < 25) s = fmaf(w2[m], wr[kh], s);
        }
        wh[(c * 25 + hh) * 3 + kw] = s;
    }
}

__device__ __forceinline__ void load_x_tile(const float* __restrict__ xbase,
                                            int o0, int h, bool hasbn,
                                            const float* ca, const float* cb,
                                            float xv[4][4])
{
    #pragma unroll
    for (int oo = 0; oo < 4; ++oo) {
        const float4 v = *reinterpret_cast<const float4*>(
            xbase + (size_t)(o0 + oo) * 25 * 512 + (size_t)h * 512);
        float tmp[4] = {v.x, v.y, v.z, v.w};
        #pragma unroll
        for (int cc = 0; cc < 4; ++cc) {
            float x = tmp[cc];
            if (hasbn) x = fmaxf(fmaf(ca[oo], x, cb[oo]), 0.0f);
            xv[oo][cc] = x;
        }
    }
}

// One block = 16 (b,w) columns; iterates the 25-step scan locally.
// out row h holds s_{24-h}  (i.e. the reference's reversed/logical order).
// If coef != null, input reads are transformed v -> relu(a[c]*v + b[c]).
__global__ __launch_bounds__(256) void scnn_kernel(const float* __restrict__ xin,
                                                   const float* __restrict__ Mt,
                                                   float* __restrict__ out,
                                                   const float* __restrict__ coef)
{
    __shared__ float prev[256 * 16];
    const int tid = threadIdx.x;
    const int og = tid >> 2, cg = tid & 3;
    const int o0 = og << 2, c0 = cg << 2;
    const int b  = blockIdx.x >> 5;
    const int w0 = (blockIdx.x & 31) << 4;

    const bool hasbn = (coef != nullptr);
    float ca[4] = {0, 0, 0, 0}, cb[4] = {0, 0, 0, 0};
    if (hasbn) {
        #pragma unroll
        for (int oo = 0; oo < 4; ++oo) {
            ca[oo] = coef[o0 + oo];
            cb[oo] = coef[256 + o0 + oo];
        }
    }

    const float* xbase = xin + (size_t)(b * 256) * 25 * 512 + w0 + c0;
    float*       obase = out + (size_t)(b * 256) * 25 * 512 + w0 + c0;

    float xv[4][4];

    // t = 0: s_0 = x_0, stored at row 24
    load_x_tile(xbase, o0, 0, hasbn, ca, cb, xv);
    #pragma unroll
    for (int oo = 0; oo < 4; ++oo) {
        #pragma unroll
        for (int cc = 0; cc < 4; ++cc) prev[(o0 + oo) * 16 + c0 + cc] = xv[oo][cc];
        float4 st = make_float4(xv[oo][0], xv[oo][1], xv[oo][2], xv[oo][3]);
        *reinterpret_cast<float4*>(obase + (size_t)(o0 + oo) * 25 * 512 + (size_t)24 * 512) = st;
    }
    __syncthreads();

    const float4* Mt4 = reinterpret_cast<const float4*>(Mt);

    for (int t = 1; t < 25; ++t) {
        load_x_tile(xbase, o0, t, hasbn, ca, cb, xv);   // issued early, hides under FMAs

        float acc[4][4];
        #pragma unroll
        for (int oo = 0; oo < 4; ++oo)
            #pragma unroll
            for (int cc = 0; cc < 4; ++cc) acc[oo][cc] = 0.f;

        #pragma unroll 4
        for (int i = 0; i < 256; ++i) {
            const float4 mv = Mt4[(i << 6) + og];                 // Mt[i][o0..o0+3]
            const float4 pv = *reinterpret_cast<const float4*>(&prev[(i << 4) + c0]);
            const float m[4] = {mv.x, mv.y, mv.z, mv.w};
            const float p[4] = {pv.x, pv.y, pv.z, pv.w};
            #pragma unroll
            for (int oo = 0; oo < 4; ++oo)
                #pragma unroll
                for (int cc = 0; cc < 4; ++cc)
                    acc[oo][cc] = fmaf(m[oo], p[cc], acc[oo][cc]);
        }
        __syncthreads();   // all prev reads complete before overwrite

        #pragma unroll
        for (int oo = 0; oo < 4; ++oo) {
            #pragma unroll
            for (int cc = 0; cc < 4; ++cc) {
                float s = xv[oo][cc] + fmaxf(acc[oo][cc], 0.0f);
                xv[oo][cc] = s;
                prev[(o0 + oo) * 16 + c0 + cc] = s;
            }
            float4 st = make_float4(xv[oo][0], xv[oo][1], xv[oo][2], xv[oo][3]);
            *reinterpret_cast<float4*>(obase + (size_t)(o0 + oo) * 25 * 512 +
                                       (size_t)(24 - t) * 512) = st;
        }
        __syncthreads();
    }
}

// Per-channel mean/var over (B,H,W) -> affine coef a[c], b[c]
__global__ __launch_bounds__(256) void stats_kernel(const float* __restrict__ buf,
                                                    const float* __restrict__ gamma,
                                                    const float* __restrict__ beta,
                                                    float* __restrict__ coef)
{
    const int c = blockIdx.x, tid = threadIdx.x;
    float s = 0.f, s2 = 0.f;
    for (int idx = tid; idx < 102400; idx += 256) {
        int b = idx / 12800;
        int rr = idx - b * 12800;
        float v = buf[(size_t)(b * 256 + c) * 12800 + rr];
        s += v; s2 += v * v;
    }
    __shared__ float ls[256], ls2[256];
    ls[tid] = s; ls2[tid] = s2;
    __syncthreads();
    for (int st = 128; st > 0; st >>= 1) {
        if (tid < st) { ls[tid] += ls[tid + st]; ls2[tid] += ls2[tid + st]; }
        __syncthreads();
    }
    if (tid == 0) {
        float mean = ls[0] * (1.0f / 102400.0f);
        float var  = ls2[0] * (1.0f / 102400.0f) - mean * mean;
        float a = gamma[c] * rsqrtf(var + 1e-5f);
        coef[c] = a;
        coef[256 + c] = beta[c] - mean * a;
    }
}

// r[b,w'] = sum_{c,hh,kw} wh[c,hh,kw] * up_w(relu(bn2(Y)))[b,c,hh,w'+kw-1]
// Block: fixed b, 8-channel chunk; 1024 threads = one w' each; atomicAdd partials.
__global__ __launch_bounds__(1024) void conv_kernel(const float* __restrict__ Y,
                                                    const float* __restrict__ coef2,
                                                    const float* __restrict__ wh,
                                                    float* __restrict__ r)
{
    const int w   = threadIdx.x;          // 0..1023
    const int b   = blockIdx.x >> 5;
    const int ch0 = (blockIdx.x & 31) << 3;
    const float scale = (float)(511.0 / 1023.0);

    int i0[3], i1[3]; float fr[3]; bool ok[3];
    #pragma unroll
    for (int kw = 0; kw < 3; ++kw) {
        int u = w + kw - 1;
        ok[kw] = (u >= 0 && u < 1024);
        int uu = ok[kw] ? u : 0;
        float pos = (float)uu * scale;
        int ii = (int)pos;
        i0[kw] = ii;
        i1[kw] = min(ii + 1, 511);
        fr[kw] = pos - (float)ii;
    }

    float acc = 0.f;
    for (int ci = 0; ci < 8; ++ci) {
        int c = ch0 + ci;
        float a = coef2[c], bo = coef2[256 + c];
        const float* whc = wh + c * 75;
        const float* rowbase = Y + (size_t)(b * 256 + c) * 25 * 512;
        for (int hh = 0; hh < 25; ++hh) {
            const float* row = rowbase + hh * 512;
            #pragma unroll
            for (int kw = 0; kw < 3; ++kw) {
                if (ok[kw]) {
                    float xa = fmaxf(fmaf(a, row[i0[kw]], bo), 0.f);
                    float xb = fmaxf(fmaf(a, row[i1[kw]], bo), 0.f);
                    float xu = fmaf(xb - xa, fr[kw], xa);
                    acc = fmaf(whc[hh * 3 + kw], xu, acc);
                }
            }
        }
    }
    atomicAdd(&r[b * 1024 + w], acc);
}

// out[b,w4] = sigmoid( up_{2048->4096}( up_{1024->2048}(r) ) )
__global__ __launch_bounds__(256) void final_kernel(const float* __restrict__ r,
                                                    float* __restrict__ out)
{
    int idx = blockIdx.x * 256 + threadIdx.x;   // 32768
    int b = idx >> 12, w4 = idx & 4095;
    const float s3 = (float)(2047.0 / 4095.0);
    const float s2 = (float)(1023.0 / 2047.0);
    const float* rb = r + b * 1024;

    float pos3 = (float)w4 * s3;
    int j0 = (int)pos3;
    float f3 = pos3 - (float)j0;
    int j1 = min(j0 + 1, 2047);

    float v[2];
    int jj[2] = {j0, j1};
    #pragma unroll
    for (int k = 0; k < 2; ++k) {
        float p = (float)jj[k] * s2;
        int i = (int)p;
        float f = p - (float)i;
        int i2 = min(i + 1, 1023);
        float lo = rb[i];
        v[k] = fmaf(rb[i2] - lo, f, lo);
    }
    float z = fmaf(v[1] - v[0], f3, v[0]);
    out[idx] = 1.0f / (1.0f + expf(-z));
}

extern "C" void kernel_launch(void* const* d_in, const int* in_sizes, int n_in,
                              void* d_out, int out_size, void* d_ws, size_t ws_size,
                              hipStream_t stream)
{
    const float* p2c   = (const float*)d_in[0];
    const float* wmsg  = (const float*)d_in[1];
    const float* gamma = (const float*)d_in[2];
    const float* beta  = (const float*)d_in[3];
    const float* wup2  = (const float*)d_in[4];
    const float* wc1   = (const float*)d_in[5];
    const float* wc2   = (const float*)d_in[6];
    float* out = (float*)d_out;
    float* ws  = (float*)d_ws;

    float* X     = ws + X_OFF;
    float* Y     = ws + Y_OFF;
    float* Mt    = ws + MT_OFF;
    float* coef1 = ws + COEF1_OFF;
    float* coef2 = ws + COEF2_OFF;
    float* wh    = ws + WH_OFF;
    float* r     = ws + R_OFF;

    hipMemsetAsync(r, 0, 8192 * sizeof(float), stream);

    prep_mt<<<256, 256, 0, stream>>>(wmsg, Mt);
    prep_wh<<<3, 256, 0, stream>>>(wup2, wc1, wc2, wh);

    // scnn1: raw input, output X (logical/reversed order)
    scnn_kernel<<<256, 256, 0, stream>>>(p2c, Mt, X, nullptr);
    stats_kernel<<<256, 256, 0, stream>>>(X, gamma, beta, coef1);

    // scnn2: reads relu(bn1(X)), output Y (logical order, raw)
    scnn_kernel<<<256, 256, 0, stream>>>(X, Mt, Y, coef1);
    stats_kernel<<<256, 256, 0, stream>>>(Y, gamma, beta, coef2);

    // folded conv + h-reduction at W=1024
    conv_kernel<<<256, 1024, 0, stream>>>(Y, coef2, wh, r);

    // two upsamples + sigmoid
    final_kernel<<<128, 256, 0, stream>>>(r, out);
}

// Round 2
// 563.050 us; speedup vs baseline: 2.0929x; 2.0929x over previous
//
#include <hip/hip_runtime.h>
#include <hip/hip_bf16.h>
#include <math.h>

// Problem: B=8, C=256, H=25, W=512
// ws layout (float offsets):
//   X     @ 0          (26,214,400)  scnn1 output, LOGICAL (reversed) order, f32
//   Y     @ 26214400   (26,214,400)  scnn2 output, logical order, f32
//   Mbf   @ 52428800   (65,536 ushort = 32,768 floats)  M row-major bf16
//   coef1 @ 52461568   (512)   bn1 affine a[c], b[c]
//   coef2 @ 52462080   (512)   bn2 affine
//   wh    @ 52462592   (19,200) folded conv/h-reduce weights [c][hh][kw]
//   r     @ 52481792   (8,192)  reduced map (8 x 1024)
// total = 52,489,984 floats = 209,959,936 bytes (< round-1's 210,091,008).

#define X_OFF      0
#define Y_OFF      26214400
#define MBF_OFF    52428800
#define COEF1_OFF  52461568
#define COEF2_OFF  52462080
#define WH_OFF     52462592
#define R_OFF      52481792

typedef __attribute__((ext_vector_type(8))) short bf16x8;  // MFMA A/B frag (8 bf16)
typedef __attribute__((ext_vector_type(4))) float f32x4;   // MFMA C/D frag

__device__ __forceinline__ ushort f2bf(float f) {          // RNE f32 -> bf16 bits
    uint32_t b = __float_as_uint(f);
    b += 0x7fffu + ((b >> 16) & 1u);
    return (ushort)(b >> 16);
}

__global__ __launch_bounds__(256) void prep_mbf(const float* __restrict__ wmsg,
                                                ushort* __restrict__ Mbf)
{
    int idx = blockIdx.x * 256 + threadIdx.x;   // o*256 + i
    float v = wmsg[(size_t)idx * 9 + 4];        // w_msg[o,i,4,0], row-major o,i
    Mbf[idx] = f2bf(v);
}

// wh[c][hh][kw] = sum_kh(valid) w2[hh-kh+1] * (sum_o w1[o]*w_up2[o,c,kh,kw])
__global__ __launch_bounds__(256) void prep_wh(const float* __restrict__ wup2,
                                               const float* __restrict__ w1,
                                               const float* __restrict__ w2,
                                               float* __restrict__ wh)
{
    const int c  = blockIdx.x / 3;
    const int kw = blockIdx.x % 3;
    const int o  = threadIdx.x;
    const float w1o = w1[o];
    __shared__ float red[3][256];
    red[0][o] = w1o * wup2[(size_t)((o * 256 + c) * 3 + 0) * 3 + kw];
    red[1][o] = w1o * wup2[(size_t)((o * 256 + c) * 3 + 1) * 3 + kw];
    red[2][o] = w1o * wup2[(size_t)((o * 256 + c) * 3 + 2) * 3 + kw];
    __syncthreads();
    for (int st = 128; st > 0; st >>= 1) {
        if (o < st) {
            red[0][o] += red[0][o + st];
            red[1][o] += red[1][o + st];
            red[2][o] += red[2][o + st];
        }
        __syncthreads();
    }
    if (o < 25) {
        float s = 0.f;
        #pragma unroll
        for (int kh = 0; kh < 3; ++kh) {
            int m = o - kh + 1;
            if (m >= 0 && m < 25) s = fmaf(w2[m], red[kh][0], s);
        }
        wh[(c * 25 + o) * 3 + kw] = s;
    }
}

// ---------------- MFMA scan ----------------
// Block = 16 (b,w) columns, 512 threads = 8 waves.
// Wave wid owns o-tiles {2*wid, 2*wid+1} (16 rows each).
// A = M (bf16, register-resident). B = prevT[c][i] bf16 in LDS (row stride 264
// ushorts = 528 B -> 2-way max bank aliasing, free). One barrier per step,
// double-buffered state; next-step x prefetched before the MFMA phase.
// out row h gets s_{24-h} (reference's reversed order).
// coef != null: input reads v -> relu(a[o]*v + b[o]).
#define LROW 264

__global__ __launch_bounds__(512, 2) void scnn_mfma(const float* __restrict__ xin,
                                                    const ushort* __restrict__ Mbf,
                                                    float* __restrict__ out,
                                                    const float* __restrict__ coef)
{
    __shared__ ushort prevT[2][16 * LROW];   // 2 x 8448 B
    const int tid   = threadIdx.x;
    const int lane  = tid & 63;
    const int wid   = tid >> 6;        // 0..7
    const int row16 = lane & 15;       // A-row (o in tile) == B-col (c) == D-col
    const int g     = lane >> 4;       // 0..3
    const int b     = blockIdx.x >> 5;
    const int w0    = (blockIdx.x & 31) << 4;
    const int to0   = wid * 2;

    // A fragments: lane holds M[(to*16+row16)][kk*32 + g*8 .. +7]
    bf16x8 afrag[2][8];
    #pragma unroll
    for (int tt = 0; tt < 2; ++tt) {
        const ushort* mrow = Mbf + (size_t)((to0 + tt) * 16 + row16) * 256 + g * 8;
        #pragma unroll
        for (int kk = 0; kk < 8; ++kk)
            afrag[tt][kk] = *reinterpret_cast<const bf16x8*>(mrow + kk * 32);
    }

    const bool hasbn = (coef != nullptr);
    float ca[2][4], cb[2][4];
    if (hasbn) {
        #pragma unroll
        for (int tt = 0; tt < 2; ++tt)
            #pragma unroll
            for (int r = 0; r < 4; ++r) {
                int o = (to0 + tt) * 16 + g * 4 + r;
                ca[tt][r] = coef[o];
                cb[tt][r] = coef[256 + o];
            }
    }

    // D frag: lane holds out[o = to*16 + g*4 + r][c = row16]
    size_t base[2][4];
    #pragma unroll
    for (int tt = 0; tt < 2; ++tt)
        #pragma unroll
        for (int r = 0; r < 4; ++r) {
            int o = (to0 + tt) * 16 + g * 4 + r;
            base[tt][r] = (size_t)(b * 256 + o) * 25 * 512 + w0 + row16;
        }

    float xv[2][4];
    #pragma unroll
    for (int tt = 0; tt < 2; ++tt)
        #pragma unroll
        for (int r = 0; r < 4; ++r) xv[tt][r] = xin[base[tt][r]];   // t = 0 row

    int p = 0;
    for (int t = 0; t < 25; ++t) {
        // prefetch x for t+1 (independent of LDS state; hides under MFMA+barrier)
        float xn[2][4];
        if (t < 24) {
            #pragma unroll
            for (int tt = 0; tt < 2; ++tt)
                #pragma unroll
                for (int r = 0; r < 4; ++r)
                    xn[tt][r] = xin[base[tt][r] + (size_t)(t + 1) * 512];
        }

        f32x4 acc[2] = {{0.f,0.f,0.f,0.f},{0.f,0.f,0.f,0.f}};
        if (t > 0) {
            const ushort* pb = &prevT[p][row16 * LROW + g * 8];
            #pragma unroll
            for (int kk = 0; kk < 8; ++kk) {
                bf16x8 bfr = *reinterpret_cast<const bf16x8*>(pb + kk * 32);
                acc[0] = __builtin_amdgcn_mfma_f32_16x16x32_bf16(afrag[0][kk], bfr, acc[0], 0, 0, 0);
                acc[1] = __builtin_amdgcn_mfma_f32_16x16x32_bf16(afrag[1][kk], bfr, acc[1], 0, 0, 0);
            }
        }

        #pragma unroll
        for (int tt = 0; tt < 2; ++tt) {
            ushort us[4];
            #pragma unroll
            for (int r = 0; r < 4; ++r) {
                float x = xv[tt][r];
                if (hasbn) x = fmaxf(fmaf(ca[tt][r], x, cb[tt][r]), 0.0f);
                float cv = x + fmaxf(acc[tt][r], 0.0f);
                out[base[tt][r] + (size_t)(24 - t) * 512] = cv;   // reversed row
                us[r] = f2bf(cv);
            }
            // prevT[c][o..o+3] for next step (bf16 state feedback)
            *reinterpret_cast<ushort4*>(
                &prevT[p ^ 1][row16 * LROW + (to0 + tt) * 16 + g * 4]) =
                make_ushort4(us[0], us[1], us[2], us[3]);
        }
        __syncthreads();
        p ^= 1;
        if (t < 24) {
            #pragma unroll
            for (int tt = 0; tt < 2; ++tt)
                #pragma unroll
                for (int r = 0; r < 4; ++r) xv[tt][r] = xn[tt][r];
        }
    }
}

// Per-channel mean/var over (B,H,W) -> affine coef a[c], b[c]
__global__ __launch_bounds__(256) void stats_kernel(const float* __restrict__ buf,
                                                    const float* __restrict__ gamma,
                                                    const float* __restrict__ beta,
                                                    float* __restrict__ coef)
{
    const int c = blockIdx.x, tid = threadIdx.x;
    float s = 0.f, s2 = 0.f;
    for (int idx = tid; idx < 102400; idx += 256) {
        int b = idx / 12800;
        int rr = idx - b * 12800;
        float v = buf[(size_t)(b * 256 + c) * 12800 + rr];
        s += v; s2 += v * v;
    }
    __shared__ float ls[256], ls2[256];
    ls[tid] = s; ls2[tid] = s2;
    __syncthreads();
    for (int st = 128; st > 0; st >>= 1) {
        if (tid < st) { ls[tid] += ls[tid + st]; ls2[tid] += ls2[tid + st]; }
        __syncthreads();
    }
    if (tid == 0) {
        float mean = ls[0] * (1.0f / 102400.0f);
        float var  = ls2[0] * (1.0f / 102400.0f) - mean * mean;
        float a = gamma[c] * rsqrtf(var + 1e-5f);
        coef[c] = a;
        coef[256 + c] = beta[c] - mean * a;
    }
}

// r[b,w'] = sum_{c,hh,kw} wh[c,hh,kw] * up_w(relu(bn2(Y)))[b,c,hh,w'+kw-1]
__global__ __launch_bounds__(1024) void conv_kernel(const float* __restrict__ Y,
                                                    const float* __restrict__ coef2,
                                                    const float* __restrict__ wh,
                                                    float* __restrict__ r)
{
    const int w   = threadIdx.x;          // 0..1023
    const int b   = blockIdx.x >> 5;
    const int ch0 = (blockIdx.x & 31) << 3;
    const float scale = (float)(511.0 / 1023.0);

    int i0[3], i1[3]; float fr[3]; bool ok[3];
    #pragma unroll
    for (int kw = 0; kw < 3; ++kw) {
        int u = w + kw - 1;
        ok[kw] = (u >= 0 && u < 1024);
        int uu = ok[kw] ? u : 0;
        float pos = (float)uu * scale;
        int ii = (int)pos;
        i0[kw] = ii;
        i1[kw] = min(ii + 1, 511);
        fr[kw] = pos - (float)ii;
    }

    float acc = 0.f;
    for (int ci = 0; ci < 8; ++ci) {
        int c = ch0 + ci;
        float a = coef2[c], bo = coef2[256 + c];
        const float* whc = wh + c * 75;
        const float* rowbase = Y + (size_t)(b * 256 + c) * 25 * 512;
        for (int hh = 0; hh < 25; ++hh) {
            const float* row = rowbase + hh * 512;
            #pragma unroll
            for (int kw = 0; kw < 3; ++kw) {
                if (ok[kw]) {
                    float xa = fmaxf(fmaf(a, row[i0[kw]], bo), 0.f);
                    float xb = fmaxf(fmaf(a, row[i1[kw]], bo), 0.f);
                    float xu = fmaf(xb - xa, fr[kw], xa);
                    acc = fmaf(whc[hh * 3 + kw], xu, acc);
                }
            }
        }
    }
    atomicAdd(&r[b * 1024 + w], acc);
}

// out[b,w4] = sigmoid( up_{2048->4096}( up_{1024->2048}(r) ) )
__global__ __launch_bounds__(256) void final_kernel(const float* __restrict__ r,
                                                    float* __restrict__ out)
{
    int idx = blockIdx.x * 256 + threadIdx.x;   // 32768
    int b = idx >> 12, w4 = idx & 4095;
    const float s3 = (float)(2047.0 / 4095.0);
    const float s2 = (float)(1023.0 / 2047.0);
    const float* rb = r + b * 1024;

    float pos3 = (float)w4 * s3;
    int j0 = (int)pos3;
    float f3 = pos3 - (float)j0;
    int j1 = min(j0 + 1, 2047);

    float v[2];
    int jj[2] = {j0, j1};
    #pragma unroll
    for (int k = 0; k < 2; ++k) {
        float p = (float)jj[k] * s2;
        int i = (int)p;
        float f = p - (float)i;
        int i2 = min(i + 1, 1023);
        float lo = rb[i];
        v[k] = fmaf(rb[i2] - lo, f, lo);
    }
    float z = fmaf(v[1] - v[0], f3, v[0]);
    out[idx] = 1.0f / (1.0f + expf(-z));
}

extern "C" void kernel_launch(void* const* d_in, const int* in_sizes, int n_in,
                              void* d_out, int out_size, void* d_ws, size_t ws_size,
                              hipStream_t stream)
{
    const float* p2c   = (const float*)d_in[0];
    const float* wmsg  = (const float*)d_in[1];
    const float* gamma = (const float*)d_in[2];
    const float* beta  = (const float*)d_in[3];
    const float* wup2  = (const float*)d_in[4];
    const float* wc1   = (const float*)d_in[5];
    const float* wc2   = (const float*)d_in[6];
    float* out = (float*)d_out;
    float* ws  = (float*)d_ws;

    float*  X     = ws + X_OFF;
    float*  Y     = ws + Y_OFF;
    ushort* Mbf   = (ushort*)(ws + MBF_OFF);
    float*  coef1 = ws + COEF1_OFF;
    float*  coef2 = ws + COEF2_OFF;
    float*  wh    = ws + WH_OFF;
    float*  r     = ws + R_OFF;

    hipMemsetAsync(r, 0, 8192 * sizeof(float), stream);

    prep_mbf<<<256, 256, 0, stream>>>(wmsg, Mbf);
    prep_wh<<<768, 256, 0, stream>>>(wup2, wc1, wc2, wh);

    // scnn1: raw input -> X (logical order)
    scnn_mfma<<<256, 512, 0, stream>>>(p2c, Mbf, X, nullptr);
    stats_kernel<<<256, 256, 0, stream>>>(X, gamma, beta, coef1);

    // scnn2: reads relu(bn1(X)) -> Y (logical order, raw)
    scnn_mfma<<<256, 512, 0, stream>>>(X, Mbf, Y, coef1);
    stats_kernel<<<256, 256, 0, stream>>>(Y, gamma, beta, coef2);

    // folded conv + h-reduction at W=1024
    conv_kernel<<<256, 1024, 0, stream>>>(Y, coef2, wh, r);

    // two upsamples + sigmoid
    final_kernel<<<128, 256, 0, stream>>>(r, out);
}

// Round 3
// 199.940 us; speedup vs baseline: 5.8938x; 2.8161x over previous
//
#include <hip/hip_runtime.h>
#include <hip/hip_bf16.h>
#include <math.h>

// Problem: B=8, C=256, H=25, W=512
// ws layout (float offsets):
//   X     @ 0          (26,214,400)  scnn1 output, LOGICAL (reversed) order, f32
//   Y     @ 26214400   (26,214,400)  scnn2 output, logical order, f32
//   Mbf   @ 52428800   (65,536 ushort = 32,768 floats)  M row-major bf16
//   coef1 @ 52461568   (512)    bn1 affine a[c], b[c]
//   coef2 @ 52462080   (512)    bn2 affine
//   wh    @ 52462592   (19,200) folded conv/h-reduce weights [c][hh][kw]
//   --- zeroed scratch zone (one memset) ---
//   r     @ 52481792   (8,192)   reduced map (8 x 1024)
//   T     @ 52489984   (12,288)  T[kw][b][v]  (3 x 8 x 512)
//   st1   @ 52502272   (512)     scnn1 output sums / sumsq
//   st2   @ 52502784   (512)     scnn2 output sums / sumsq
// total = 52,503,296 floats = 210,013,184 bytes of d_ws.

#define X_OFF      0
#define Y_OFF      26214400
#define MBF_OFF    52428800
#define COEF1_OFF  52461568
#define COEF2_OFF  52462080
#define WH_OFF     52462592
#define R_OFF      52481792
#define T_OFF      52489984
#define ST1_OFF    52502272
#define ST2_OFF    52502784
#define ZERO_ZONE_FLOATS 21504

typedef __attribute__((ext_vector_type(8))) short bf16x8;  // MFMA A/B frag (8 bf16)
typedef __attribute__((ext_vector_type(4))) float f32x4;   // MFMA C/D frag

__device__ __forceinline__ ushort f2bf(float f) {          // RNE f32 -> bf16 bits
    uint32_t b = __float_as_uint(f);
    b += 0x7fffu + ((b >> 16) & 1u);
    return (ushort)(b >> 16);
}

__global__ __launch_bounds__(256) void prep_mbf(const float* __restrict__ wmsg,
                                                ushort* __restrict__ Mbf)
{
    int idx = blockIdx.x * 256 + threadIdx.x;   // o*256 + i
    float v = wmsg[(size_t)idx * 9 + 4];        // w_msg[o,i,4,0]
    Mbf[idx] = f2bf(v);
}

// wh[c][hh][kw] = sum_kh(valid) w2[hh-kh+1] * (sum_o w1[o]*w_up2[o,c,kh,kw])
__global__ __launch_bounds__(256) void prep_wh(const float* __restrict__ wup2,
                                               const float* __restrict__ w1,
                                               const float* __restrict__ w2,
                                               float* __restrict__ wh)
{
    const int c  = blockIdx.x / 3;
    const int kw = blockIdx.x % 3;
    const int o  = threadIdx.x;
    const float w1o = w1[o];
    __shared__ float red[3][256];
    red[0][o] = w1o * wup2[(size_t)((o * 256 + c) * 3 + 0) * 3 + kw];
    red[1][o] = w1o * wup2[(size_t)((o * 256 + c) * 3 + 1) * 3 + kw];
    red[2][o] = w1o * wup2[(size_t)((o * 256 + c) * 3 + 2) * 3 + kw];
    __syncthreads();
    for (int st = 128; st > 0; st >>= 1) {
        if (o < st) {
            red[0][o] += red[0][o + st];
            red[1][o] += red[1][o + st];
            red[2][o] += red[2][o + st];
        }
        __syncthreads();
    }
    if (o < 25) {
        float s = 0.f;
        #pragma unroll
        for (int kh = 0; kh < 3; ++kh) {
            int m = o - kh + 1;
            if (m >= 0 && m < 25) s = fmaf(w2[m], red[kh][0], s);
        }
        wh[(c * 25 + o) * 3 + kw] = s;
    }
}

// ---------------- MFMA scan (+ fused output stats) ----------------
// Block = 16 (b,w) columns, 512 threads = 8 waves; wave wid owns o-tiles
// {2wid, 2wid+1}. A = M bf16 register-resident; B = prevT bf16 in LDS
// (row stride 264 ushorts -> max 2-way bank aliasing, free). One barrier/step.
// out row h gets s_{24-h} (reference's reversed order).
// coef != null: input reads v -> relu(a[o]*v + b[o]).
// stats: atomicAdd per-channel {sum, sumsq} of raw outputs.
#define LROW 264

__global__ __launch_bounds__(512, 2) void scnn_mfma(const float* __restrict__ xin,
                                                    const ushort* __restrict__ Mbf,
                                                    float* __restrict__ out,
                                                    const float* __restrict__ coef,
                                                    float* __restrict__ stats)
{
    __shared__ ushort prevT[2][16 * LROW];
    const int tid   = threadIdx.x;
    const int lane  = tid & 63;
    const int wid   = tid >> 6;        // 0..7
    const int row16 = lane & 15;       // A-row == B-col (w within tile) == D-col
    const int g     = lane >> 4;       // 0..3
    const int b     = blockIdx.x >> 5;
    const int w0    = (blockIdx.x & 31) << 4;
    const int to0   = wid * 2;

    bf16x8 afrag[2][8];
    #pragma unroll
    for (int tt = 0; tt < 2; ++tt) {
        const ushort* mrow = Mbf + (size_t)((to0 + tt) * 16 + row16) * 256 + g * 8;
        #pragma unroll
        for (int kk = 0; kk < 8; ++kk)
            afrag[tt][kk] = *reinterpret_cast<const bf16x8*>(mrow + kk * 32);
    }

    const bool hasbn = (coef != nullptr);
    float ca[2][4], cb[2][4];
    if (hasbn) {
        #pragma unroll
        for (int tt = 0; tt < 2; ++tt)
            #pragma unroll
            for (int r = 0; r < 4; ++r) {
                int o = (to0 + tt) * 16 + g * 4 + r;
                ca[tt][r] = coef[o];
                cb[tt][r] = coef[256 + o];
            }
    }

    size_t base[2][4];
    #pragma unroll
    for (int tt = 0; tt < 2; ++tt)
        #pragma unroll
        for (int r = 0; r < 4; ++r) {
            int o = (to0 + tt) * 16 + g * 4 + r;
            base[tt][r] = (size_t)(b * 256 + o) * 25 * 512 + w0 + row16;
        }

    float xv[2][4];
    #pragma unroll
    for (int tt = 0; tt < 2; ++tt)
        #pragma unroll
        for (int r = 0; r < 4; ++r) xv[tt][r] = xin[base[tt][r]];

    float s1[2][4] = {{0,0,0,0},{0,0,0,0}};
    float sq[2][4] = {{0,0,0,0},{0,0,0,0}};

    int p = 0;
    for (int t = 0; t < 25; ++t) {
        float xn[2][4];
        if (t < 24) {
            #pragma unroll
            for (int tt = 0; tt < 2; ++tt)
                #pragma unroll
                for (int r = 0; r < 4; ++r)
                    xn[tt][r] = xin[base[tt][r] + (size_t)(t + 1) * 512];
        }

        f32x4 acc[2] = {{0.f,0.f,0.f,0.f},{0.f,0.f,0.f,0.f}};
        if (t > 0) {
            const ushort* pb = &prevT[p][row16 * LROW + g * 8];
            #pragma unroll
            for (int kk = 0; kk < 8; ++kk) {
                bf16x8 bfr = *reinterpret_cast<const bf16x8*>(pb + kk * 32);
                acc[0] = __builtin_amdgcn_mfma_f32_16x16x32_bf16(afrag[0][kk], bfr, acc[0], 0, 0, 0);
                acc[1] = __builtin_amdgcn_mfma_f32_16x16x32_bf16(afrag[1][kk], bfr, acc[1], 0, 0, 0);
            }
        }

        #pragma unroll
        for (int tt = 0; tt < 2; ++tt) {
            ushort us[4];
            #pragma unroll
            for (int r = 0; r < 4; ++r) {
                float x = xv[tt][r];
                if (hasbn) x = fmaxf(fmaf(ca[tt][r], x, cb[tt][r]), 0.0f);
                float cv = x + fmaxf(acc[tt][r], 0.0f);
                out[base[tt][r] + (size_t)(24 - t) * 512] = cv;
                s1[tt][r] += cv;
                sq[tt][r] = fmaf(cv, cv, sq[tt][r]);
                us[r] = f2bf(cv);
            }
            *reinterpret_cast<ushort4*>(
                &prevT[p ^ 1][row16 * LROW + (to0 + tt) * 16 + g * 4]) =
                make_ushort4(us[0], us[1], us[2], us[3]);
        }
        __syncthreads();
        p ^= 1;
        if (t < 24) {
            #pragma unroll
            for (int tt = 0; tt < 2; ++tt)
                #pragma unroll
                for (int r = 0; r < 4; ++r) xv[tt][r] = xn[tt][r];
        }
    }

    // fused per-channel stats: reduce across the 16 lanes sharing one o
    #pragma unroll
    for (int tt = 0; tt < 2; ++tt)
        #pragma unroll
        for (int r = 0; r < 4; ++r) {
            float a = s1[tt][r], q = sq[tt][r];
            #pragma unroll
            for (int m = 8; m >= 1; m >>= 1) {
                a += __shfl_xor(a, m, 64);
                q += __shfl_xor(q, m, 64);
            }
            if (row16 == 0) {
                int o = (to0 + tt) * 16 + g * 4 + r;
                atomicAdd(&stats[o], a);
                atomicAdd(&stats[256 + o], q);
            }
        }
}

__global__ __launch_bounds__(256) void coef_kernel(const float* __restrict__ stats,
                                                   const float* __restrict__ gamma,
                                                   const float* __restrict__ beta,
                                                   float* __restrict__ coef)
{
    int c = threadIdx.x;
    float mean = stats[c] * (1.0f / 102400.0f);
    float var  = stats[256 + c] * (1.0f / 102400.0f) - mean * mean;
    float a = gamma[c] * rsqrtf(var + 1e-5f);
    coef[c] = a;
    coef[256 + c] = beta[c] - mean * a;
}

// T[kw][b][v] = sum_{c,hh} wh[c,hh,kw] * relu(bn2(Y[b,c,hh,v]))
// Block = (b, 8-channel chunk); 512 threads = one v each; coalesced rows.
__global__ __launch_bounds__(512) void conv_reduce(const float* __restrict__ Y,
                                                   const float* __restrict__ coef2,
                                                   const float* __restrict__ wh,
                                                   float* __restrict__ T)
{
    const int v  = threadIdx.x;            // 0..511
    const int b  = blockIdx.x >> 5;
    const int c0 = (blockIdx.x & 31) << 3;

    __shared__ float whL[8][25][3];
    for (int i = threadIdx.x; i < 600; i += 512) {
        int ci = i / 75, rem = i % 75;
        whL[ci][rem / 3][rem % 3] = wh[(c0 + ci) * 75 + rem];
    }
    __syncthreads();

    float a0 = 0.f, a1 = 0.f, a2 = 0.f;
    for (int ci = 0; ci < 8; ++ci) {
        int c = c0 + ci;
        float a = coef2[c], bo = coef2[256 + c];
        const float* rowb = Y + (size_t)(b * 256 + c) * 12800 + v;
        #pragma unroll 5
        for (int hh = 0; hh < 25; ++hh) {
            float y = rowb[hh * 512];
            float z = fmaxf(fmaf(a, y, bo), 0.f);
            a0 = fmaf(whL[ci][hh][0], z, a0);
            a1 = fmaf(whL[ci][hh][1], z, a1);
            a2 = fmaf(whL[ci][hh][2], z, a2);
        }
    }
    atomicAdd(&T[(0 * 8 + b) * 512 + v], a0);
    atomicAdd(&T[(1 * 8 + b) * 512 + v], a1);
    atomicAdd(&T[(2 * 8 + b) * 512 + v], a2);
}

// r[b,w'] = sum_kw (valid u=w'+kw-1) interp_512->1024(T[kw][b])[u]
__global__ __launch_bounds__(256) void combine_r(const float* __restrict__ T,
                                                 float* __restrict__ r)
{
    int idx = blockIdx.x * 256 + threadIdx.x;   // 8192
    int b = idx >> 10, w = idx & 1023;
    const float scale = (float)(511.0 / 1023.0);
    float acc = 0.f;
    #pragma unroll
    for (int kw = 0; kw < 3; ++kw) {
        int u = w + kw - 1;
        if (u >= 0 && u < 1024) {
            float pos = (float)u * scale;
            int i0 = (int)pos;
            float f = pos - (float)i0;
            int i1 = min(i0 + 1, 511);
            const float* Tk = T + (size_t)(kw * 8 + b) * 512;
            float lo = Tk[i0];
            acc += fmaf(Tk[i1] - lo, f, lo);
        }
    }
    r[idx] = acc;
}

// out[b,w4] = sigmoid( up_{2048->4096}( up_{1024->2048}(r) ) )
__global__ __launch_bounds__(256) void final_kernel(const float* __restrict__ r,
                                                    float* __restrict__ out)
{
    int idx = blockIdx.x * 256 + threadIdx.x;   // 32768
    int b = idx >> 12, w4 = idx & 4095;
    const float s3 = (float)(2047.0 / 4095.0);
    const float s2 = (float)(1023.0 / 2047.0);
    const float* rb = r + b * 1024;

    float pos3 = (float)w4 * s3;
    int j0 = (int)pos3;
    float f3 = pos3 - (float)j0;
    int j1 = min(j0 + 1, 2047);

    float v[2];
    int jj[2] = {j0, j1};
    #pragma unroll
    for (int k = 0; k < 2; ++k) {
        float p = (float)jj[k] * s2;
        int i = (int)p;
        float f = p - (float)i;
        int i2 = min(i + 1, 1023);
        float lo = rb[i];
        v[k] = fmaf(rb[i2] - lo, f, lo);
    }
    float z = fmaf(v[1] - v[0], f3, v[0]);
    out[idx] = 1.0f / (1.0f + expf(-z));
}

extern "C" void kernel_launch(void* const* d_in, const int* in_sizes, int n_in,
                              void* d_out, int out_size, void* d_ws, size_t ws_size,
                              hipStream_t stream)
{
    const float* p2c   = (const float*)d_in[0];
    const float* wmsg  = (const float*)d_in[1];
    const float* gamma = (const float*)d_in[2];
    const float* beta  = (const float*)d_in[3];
    const float* wup2  = (const float*)d_in[4];
    const float* wc1   = (const float*)d_in[5];
    const float* wc2   = (const float*)d_in[6];
    float* out = (float*)d_out;
    float* ws  = (float*)d_ws;

    float*  X     = ws + X_OFF;
    float*  Y     = ws + Y_OFF;
    ushort* Mbf   = (ushort*)(ws + MBF_OFF);
    float*  coef1 = ws + COEF1_OFF;
    float*  coef2 = ws + COEF2_OFF;
    float*  wh    = ws + WH_OFF;
    float*  r     = ws + R_OFF;
    float*  T     = ws + T_OFF;
    float*  st1   = ws + ST1_OFF;
    float*  st2   = ws + ST2_OFF;

    hipMemsetAsync(r, 0, ZERO_ZONE_FLOATS * sizeof(float), stream);  // r,T,st1,st2

    prep_mbf<<<256, 256, 0, stream>>>(wmsg, Mbf);
    prep_wh<<<768, 256, 0, stream>>>(wup2, wc1, wc2, wh);

    // scnn1: raw input -> X (logical order) + stats
    scnn_mfma<<<256, 512, 0, stream>>>(p2c, Mbf, X, nullptr, st1);
    coef_kernel<<<1, 256, 0, stream>>>(st1, gamma, beta, coef1);

    // scnn2: reads relu(bn1(X)) -> Y + stats
    scnn_mfma<<<256, 512, 0, stream>>>(X, Mbf, Y, coef1, st2);
    coef_kernel<<<1, 256, 0, stream>>>(st2, gamma, beta, coef2);

    // folded conv + h-reduction, decomposed through the linear upsample
    conv_reduce<<<256, 512, 0, stream>>>(Y, coef2, wh, T);
    combine_r<<<32, 256, 0, stream>>>(T, r);

    // two upsamples + sigmoid
    final_kernel<<<128, 256, 0, stream>>>(r, out);
}

// Round 5
// 176.787 us; speedup vs baseline: 6.6657x; 1.1310x over previous
//
#include <hip/hip_runtime.h>
#include <math.h>

// Problem: B=8, C=256, H=25, W=512   (N = B*C*H*W = 26,214,400 elements)
// ws layout (float-slot offsets; bf16 arrays use 2 elements per slot):
//   Xbf   @ 0          (26,214,400 ushort = 13,107,200 slots) scnn1 out, bf16
//   Ybf   @ 13107200   (26,214,400 ushort = 13,107,200 slots) scnn2 out, bf16
//   Mbf   @ 26214400   (65,536 ushort = 32,768 slots)  M row-major bf16
//   coef1 @ 26247168   (512)    bn1 affine a[c], b[c]
//   coef2 @ 26247680   (512)    bn2 affine
//   wh    @ 26248192   (19,200) folded conv/h-reduce weights [c][hh][kw]
//   --- zeroed zone (one memset: 13,312 floats) ---
//   T     @ 26267392   (12,288) T[kw][b][v]
//   st1   @ 26279680   (512)    scnn1 sums/sumsq
//   st2   @ 26280192   (512)    scnn2 sums/sumsq
//   --- end zero zone ---
//   r     @ 26280704   (8,192)  reduced map (8 x 1024), fully overwritten
// total = 26,288,896 floats = 105,155,584 bytes of d_ws.

#define XBF_OFF    0
#define YBF_OFF    13107200
#define MBF_OFF    26214400
#define COEF1_OFF  26247168
#define COEF2_OFF  26247680
#define WH_OFF     26248192
#define T_OFF      26267392
#define ST1_OFF    26279680
#define ST2_OFF    26280192
#define R_OFF      26280704
#define ZERO_FLOATS 13312

typedef __attribute__((ext_vector_type(8))) short bf16x8;  // MFMA A/B frag
typedef __attribute__((ext_vector_type(4))) float f32x4;   // MFMA C/D frag

__device__ __forceinline__ ushort f2bf(float f) {          // RNE f32 -> bf16 bits
    uint32_t b = __float_as_uint(f);
    b += 0x7fffu + ((b >> 16) & 1u);
    return (ushort)(b >> 16);
}
__device__ __forceinline__ float bf2f(ushort u) {
    return __uint_as_float((uint32_t)u << 16);
}

__global__ __launch_bounds__(256) void prep_mbf(const float* __restrict__ wmsg,
                                                ushort* __restrict__ Mbf)
{
    int idx = blockIdx.x * 256 + threadIdx.x;   // o*256 + i
    Mbf[idx] = f2bf(wmsg[(size_t)idx * 9 + 4]); // w_msg[o,i,4,0]
}

// wh[c][hh][kw] = sum_kh(valid) w2[hh-kh+1] * (sum_o w1[o]*w_up2[o,c,kh,kw])
__global__ __launch_bounds__(256) void prep_wh(const float* __restrict__ wup2,
                                               const float* __restrict__ w1,
                                               const float* __restrict__ w2,
                                               float* __restrict__ wh)
{
    const int c  = blockIdx.x / 3;
    const int kw = blockIdx.x % 3;
    const int o  = threadIdx.x;
    const float w1o = w1[o];
    __shared__ float red[3][256];
    red[0][o] = w1o * wup2[(size_t)((o * 256 + c) * 3 + 0) * 3 + kw];
    red[1][o] = w1o * wup2[(size_t)((o * 256 + c) * 3 + 1) * 3 + kw];
    red[2][o] = w1o * wup2[(size_t)((o * 256 + c) * 3 + 2) * 3 + kw];
    __syncthreads();
    for (int st = 128; st > 0; st >>= 1) {
        if (o < st) {
            red[0][o] += red[0][o + st];
            red[1][o] += red[1][o + st];
            red[2][o] += red[2][o + st];
        }
        __syncthreads();
    }
    if (o < 25) {
        float s = 0.f;
        #pragma unroll
        for (int kh = 0; kh < 3; ++kh) {
            int m = o - kh + 1;
            if (m >= 0 && m < 25) s = fmaf(w2[m], red[kh][0], s);
        }
        wh[(c * 25 + o) * 3 + kw] = s;
    }
}

// ---------------- MFMA scan (+ fused output stats) ----------------
// Block = 16 (b,w) columns, 512 threads = 8 waves; wave wid owns o-tiles
// {2wid, 2wid+1}. A = M bf16 register-resident. State tile in LDS stored in
// B-FRAGMENT ORDER: chunk[kk][lane] = 16B holding channels kk*32+(lane>>4)*8+j,
// col lane&15 -> ds_read_b128 is 2-way (free). Byte addrs XOR-swizzled
// (bit5 ^= bit8) to de-conflict the ushort4 writes. One raw s_barrier +
// lgkmcnt(0) per step (NO vmcnt drain -> prefetch/stores span steps).
// x prefetched 2 steps deep. out row h gets s_{24-h} (reversed order), bf16.
// coef != null: input v -> relu(a[o]*v + b[o]).
template <bool INBF>
__global__ __launch_bounds__(512, 2) void scnn_mfma(const void* __restrict__ xin_,
                                                    const ushort* __restrict__ Mbf,
                                                    ushort* __restrict__ outb,
                                                    const float* __restrict__ coef,
                                                    float* __restrict__ stats)
{
    __shared__ ulong2 lds_[1024];          // 16 KB, 16B aligned
    char* lds = (char*)lds_;
    const float*  xf = (const float*)xin_;
    const ushort* xh = (const ushort*)xin_;

    const int tid   = threadIdx.x;
    const int lane  = tid & 63;
    const int wid   = tid >> 6;        // 0..7
    const int row16 = lane & 15;       // A-row == B-col == D-col
    const int g     = lane >> 4;       // 0..3
    const int b     = blockIdx.x >> 5;
    const int w0    = (blockIdx.x & 31) << 4;
    const int to0   = wid * 2;

    // LDS read base (per-lane, swizzled); chunk kk at +kk*1024, buffer p at +p*8192
    const int lofs = (lane * 16) ^ (((lane >> 4) & 1) << 5);
    // LDS write offsets: target reader-lane L=(tt*2+(g>>1))*16+row16, byte (g&1)*8
    int woff[2];
    #pragma unroll
    for (int tt = 0; tt < 2; ++tt) {
        int inner = (tt * 2 + (g >> 1)) * 256 + row16 * 16 + (g & 1) * 8;
        woff[tt] = wid * 1024 + (inner ^ (((inner >> 8) & 1) << 5));
    }

    // A fragments: lane holds M[(to*16+row16)][kk*32 + g*8 .. +7]
    bf16x8 afrag[2][8];
    #pragma unroll
    for (int tt = 0; tt < 2; ++tt) {
        const ushort* mrow = Mbf + (size_t)((to0 + tt) * 16 + row16) * 256 + g * 8;
        #pragma unroll
        for (int kk = 0; kk < 8; ++kk)
            afrag[tt][kk] = *reinterpret_cast<const bf16x8*>(mrow + kk * 32);
    }

    const bool hasbn = (coef != nullptr);
    float ca[2][4], cb[2][4];
    if (hasbn) {
        #pragma unroll
        for (int tt = 0; tt < 2; ++tt)
            #pragma unroll
            for (int r = 0; r < 4; ++r) {
                int o = (to0 + tt) * 16 + g * 4 + r;
                ca[tt][r] = coef[o];
                cb[tt][r] = coef[256 + o];
            }
    }

    size_t base[2][4];
    #pragma unroll
    for (int tt = 0; tt < 2; ++tt)
        #pragma unroll
        for (int r = 0; r < 4; ++r) {
            int o = (to0 + tt) * 16 + g * 4 + r;
            base[tt][r] = (size_t)(b * 256 + o) * 25 * 512 + w0 + row16;
        }

    // x state held as raw bits (convert at USE so waitcnts stay late)
    uint xv[2][4], xn[2][4];
    #define LDX(t, dst)                                                        \
        { _Pragma("unroll") for (int tt = 0; tt < 2; ++tt)                     \
          _Pragma("unroll") for (int r = 0; r < 4; ++r) {                      \
              size_t a = base[tt][r] + (size_t)(t) * 512;                      \
              dst[tt][r] = INBF ? (uint)xh[a] : __float_as_uint(xf[a]);        \
          } }

    LDX(0, xv);
    LDX(1, xn);

    float s1[2][4] = {{0,0,0,0},{0,0,0,0}};
    float sq[2][4] = {{0,0,0,0},{0,0,0,0}};

    int p = 0;
    for (int t = 0; t < 25; ++t) {
        uint x2[2][4] = {{0,0,0,0},{0,0,0,0}};
        if (t < 23) LDX(t + 2, x2);     // depth-2 prefetch

        f32x4 acc[2] = {{0.f,0.f,0.f,0.f},{0.f,0.f,0.f,0.f}};
        if (t > 0) {
            const char* pb = lds + p * 8192 + lofs;
            #pragma unroll
            for (int kk = 0; kk < 8; ++kk) {
                bf16x8 bfr = *reinterpret_cast<const bf16x8*>(pb + kk * 1024);
                acc[0] = __builtin_amdgcn_mfma_f32_16x16x32_bf16(afrag[0][kk], bfr, acc[0], 0, 0, 0);
                acc[1] = __builtin_amdgcn_mfma_f32_16x16x32_bf16(afrag[1][kk], bfr, acc[1], 0, 0, 0);
            }
        }

        char* wb = lds + (p ^ 1) * 8192;
        #pragma unroll
        for (int tt = 0; tt < 2; ++tt) {
            ushort us[4];
            #pragma unroll
            for (int r = 0; r < 4; ++r) {
                float x = INBF ? bf2f((ushort)xv[tt][r]) : __uint_as_float(xv[tt][r]);
                if (hasbn) x = fmaxf(fmaf(ca[tt][r], x, cb[tt][r]), 0.0f);
                float cv = x + fmaxf(acc[tt][r], 0.0f);
                us[r] = f2bf(cv);
                outb[base[tt][r] + (size_t)(24 - t) * 512] = us[r];
                s1[tt][r] += cv;
                sq[tt][r] = fmaf(cv, cv, sq[tt][r]);
            }
            *reinterpret_cast<ushort4*>(wb + woff[tt]) =
                make_ushort4(us[0], us[1], us[2], us[3]);
        }

        // LDS-only barrier: order ds_write -> barrier; vmcnt NOT drained.
        asm volatile("s_waitcnt lgkmcnt(0)" ::: "memory");
        __builtin_amdgcn_s_barrier();
        __builtin_amdgcn_sched_barrier(0);

        p ^= 1;
        #pragma unroll
        for (int tt = 0; tt < 2; ++tt)
            #pragma unroll
            for (int r = 0; r < 4; ++r) { xv[tt][r] = xn[tt][r]; xn[tt][r] = x2[tt][r]; }
    }

    // fused per-channel stats: reduce across the 16 lanes sharing one o
    #pragma unroll
    for (int tt = 0; tt < 2; ++tt)
        #pragma unroll
        for (int r = 0; r < 4; ++r) {
            float a = s1[tt][r], q = sq[tt][r];
            #pragma unroll
            for (int m = 8; m >= 1; m >>= 1) {
                a += __shfl_xor(a, m, 64);
                q += __shfl_xor(q, m, 64);
            }
            if (row16 == 0) {
                int o = (to0 + tt) * 16 + g * 4 + r;
                atomicAdd(&stats[o], a);
                atomicAdd(&stats[256 + o], q);
            }
        }
}

__global__ __launch_bounds__(256) void coef_kernel(const float* __restrict__ stats,
                                                   const float* __restrict__ gamma,
                                                   const float* __restrict__ beta,
                                                   float* __restrict__ coef)
{
    int c = threadIdx.x;
    float mean = stats[c] * (1.0f / 102400.0f);
    float var  = stats[256 + c] * (1.0f / 102400.0f) - mean * mean;
    float a = gamma[c] * rsqrtf(var + 1e-5f);
    coef[c] = a;
    coef[256 + c] = beta[c] - mean * a;
}

// T[kw][b][v] = sum_{c,hh} wh[c,hh,kw] * relu(bn2(Y[b,c,hh,v])), Y in bf16.
// Block = (b, 8-channel chunk); 256 threads, 2 v each (uint = bf16x2 loads).
__global__ __launch_bounds__(256) void conv_reduce(const ushort* __restrict__ Y,
                                                   const float* __restrict__ coef2,
                                                   const float* __restrict__ wh,
                                                   float* __restrict__ T)
{
    const int v2 = threadIdx.x;            // v = 2*v2, 2*v2+1
    const int b  = blockIdx.x >> 5;
    const int c0 = (blockIdx.x & 31) << 3;

    __shared__ float whL[8][25][3];
    for (int i = threadIdx.x; i < 600; i += 256) {
        int ci = i / 75, rem = i % 75;
        whL[ci][rem / 3][rem % 3] = wh[(c0 + ci) * 75 + rem];
    }
    __syncthreads();

    float a0[2] = {0,0}, a1[2] = {0,0}, a2[2] = {0,0};
    for (int ci = 0; ci < 8; ++ci) {
        int c = c0 + ci;
        float sa = coef2[c], bo = coef2[256 + c];
        const uint* rowb = (const uint*)(Y + (size_t)(b * 256 + c) * 12800) + v2;
        #pragma unroll 5
        for (int hh = 0; hh < 25; ++hh) {
            uint yy = rowb[hh * 256];
            float z0 = fmaxf(fmaf(sa, bf2f((ushort)(yy & 0xffffu)), bo), 0.f);
            float z1 = fmaxf(fmaf(sa, bf2f((ushort)(yy >> 16)),     bo), 0.f);
            float wc0 = whL[ci][hh][0], wc1 = whL[ci][hh][1], wc2 = whL[ci][hh][2];
            a0[0] = fmaf(wc0, z0, a0[0]); a0[1] = fmaf(wc0, z1, a0[1]);
            a1[0] = fmaf(wc1, z0, a1[0]); a1[1] = fmaf(wc1, z1, a1[1]);
            a2[0] = fmaf(wc2, z0, a2[0]); a2[1] = fmaf(wc2, z1, a2[1]);
        }
    }
    const int vb = 2 * v2;
    atomicAdd(&T[(0 * 8 + b) * 512 + vb],     a0[0]);
    atomicAdd(&T[(0 * 8 + b) * 512 + vb + 1], a0[1]);
    atomicAdd(&T[(1 * 8 + b) * 512 + vb],     a1[0]);
    atomicAdd(&T[(1 * 8 + b) * 512 + vb + 1], a1[1]);
    atomicAdd(&T[(2 * 8 + b) * 512 + vb],     a2[0]);
    atomicAdd(&T[(2 * 8 + b) * 512 + vb + 1], a2[1]);
}

// r[b,w'] = sum_kw (valid u=w'+kw-1) interp_512->1024(T[kw][b])[u]
__global__ __launch_bounds__(256) void combine_r(const float* __restrict__ T,
                                                 float* __restrict__ r)
{
    int idx = blockIdx.x * 256 + threadIdx.x;   // 8192
    int b = idx >> 10, w = idx & 1023;
    const float scale = (float)(511.0 / 1023.0);
    float acc = 0.f;
    #pragma unroll
    for (int kw = 0; kw < 3; ++kw) {
        int u = w + kw - 1;
        if (u >= 0 && u < 1024) {
            float pos = (float)u * scale;
            int i0 = (int)pos;
            float f = pos - (float)i0;
            int i1 = min(i0 + 1, 511);
            const float* Tk = T + (size_t)(kw * 8 + b) * 512;
            float lo = Tk[i0];
            acc += fmaf(Tk[i1] - lo, f, lo);
        }
    }
    r[idx] = acc;
}

// out[b,w4] = sigmoid( up_{2048->4096}( up_{1024->2048}(r) ) )
__global__ __launch_bounds__(256) void final_kernel(const float* __restrict__ r,
                                                    float* __restrict__ out)
{
    int idx = blockIdx.x * 256 + threadIdx.x;   // 32768
    int b = idx >> 12, w4 = idx & 4095;
    const float s3 = (float)(2047.0 / 4095.0);
    const float s2 = (float)(1023.0 / 2047.0);
    const float* rb = r + b * 1024;

    float pos3 = (float)w4 * s3;
    int j0 = (int)pos3;
    float f3 = pos3 - (float)j0;
    int j1 = min(j0 + 1, 2047);

    float v[2];
    int jj[2] = {j0, j1};
    #pragma unroll
    for (int k = 0; k < 2; ++k) {
        float p = (float)jj[k] * s2;
        int i = (int)p;
        float f = p - (float)i;
        int i2 = min(i + 1, 1023);
        float lo = rb[i];
        v[k] = fmaf(rb[i2] - lo, f, lo);
    }
    float z = fmaf(v[1] - v[0], f3, v[0]);
    out[idx] = 1.0f / (1.0f + expf(-z));
}

extern "C" void kernel_launch(void* const* d_in, const int* in_sizes, int n_in,
                              void* d_out, int out_size, void* d_ws, size_t ws_size,
                              hipStream_t stream)
{
    const float* p2c   = (const float*)d_in[0];
    const float* wmsg  = (const float*)d_in[1];
    const float* gamma = (const float*)d_in[2];
    const float* beta  = (const float*)d_in[3];
    const float* wup2  = (const float*)d_in[4];
    const float* wc1   = (const float*)d_in[5];
    const float* wc2   = (const float*)d_in[6];
    float* out = (float*)d_out;
    float* ws  = (float*)d_ws;

    ushort* Xbf   = (ushort*)(ws + XBF_OFF);
    ushort* Ybf   = (ushort*)(ws + YBF_OFF);
    ushort* Mbf   = (ushort*)(ws + MBF_OFF);
    float*  coef1 = ws + COEF1_OFF;
    float*  coef2 = ws + COEF2_OFF;
    float*  wh    = ws + WH_OFF;
    float*  T     = ws + T_OFF;
    float*  st1   = ws + ST1_OFF;
    float*  st2   = ws + ST2_OFF;
    float*  r     = ws + R_OFF;

    hipMemsetAsync(T, 0, ZERO_FLOATS * sizeof(float), stream);  // T, st1, st2

    prep_mbf<<<256, 256, 0, stream>>>(wmsg, Mbf);
    prep_wh<<<768, 256, 0, stream>>>(wup2, wc1, wc2, wh);

    // scnn1: f32 input -> Xbf (bf16, logical order) + stats
    scnn_mfma<false><<<256, 512, 0, stream>>>(p2c, Mbf, Xbf, nullptr, st1);
    coef_kernel<<<1, 256, 0, stream>>>(st1, gamma, beta, coef1);

    // scnn2: reads relu(bn1(Xbf)) -> Ybf + stats
    scnn_mfma<true><<<256, 512, 0, stream>>>(Xbf, Mbf, Ybf, coef1, st2);
    coef_kernel<<<1, 256, 0, stream>>>(st2, gamma, beta, coef2);

    // folded conv + h-reduction, decomposed through the linear upsample
    conv_reduce<<<256, 256, 0, stream>>>(Ybf, coef2, wh, T);
    combine_r<<<32, 256, 0, stream>>>(T, r);

    // two upsamples + sigmoid
    final_kernel<<<128, 256, 0, stream>>>(r, out);
}